// Round 3
// baseline (300.246 us; speedup 1.0000x reference)
//
#include <hip/hip_runtime.h>
#include <stdint.h>

#define V 128000
#define NBINS 4096
#define CAP 4096
#define NTHREADS 1024

typedef unsigned int u32;
typedef unsigned long long u64;

__device__ __forceinline__ u32 rotl32(u32 x, int r) { return (x << r) | (x >> (32 - r)); }

// JAX threefry2x32 with key = (0, 1)  [jax.random.key(1)]
__device__ __forceinline__ void threefry01(u32 c0, u32 c1, u32& o0, u32& o1) {
    const u32 ks0 = 0u, ks1 = 1u, ks2 = 0x1BD11BDBu;  // 0^1^0x1BD11BDA
    u32 x0 = c0 + ks0;
    u32 x1 = c1 + ks1;
#define TFR(r) { x0 += x1; x1 = rotl32(x1, r); x1 ^= x0; }
    TFR(13) TFR(15) TFR(26) TFR(6)
    x0 += ks1; x1 += ks2 + 1u;
    TFR(17) TFR(29) TFR(16) TFR(24)
    x0 += ks2; x1 += ks0 + 2u;
    TFR(13) TFR(15) TFR(26) TFR(6)
    x0 += ks0; x1 += ks1 + 3u;
    TFR(17) TFR(29) TFR(16) TFR(24)
    x0 += ks1; x1 += ks2 + 4u;
    TFR(13) TFR(15) TFR(26) TFR(6)
    x0 += ks2; x1 += ks0 + 5u;
#undef TFR
    o0 = x0; o1 = x1;
}

__device__ __forceinline__ u32 mapkey(float f) {
    u32 b = __float_as_uint(f);
    return b ^ ((b & 0x80000000u) ? 0xFFFFFFFFu : 0x80000000u);
}
__device__ __forceinline__ float unmapkey(u32 k) {
    u32 b = (k & 0x80000000u) ? (k ^ 0x80000000u) : (k ^ 0xFFFFFFFFu);
    return __uint_as_float(b);
}

// top_ks may be laid out as int64 or int32. Under int64-LE, int32 words
// 1,3,5,7 are high words of values <=1000 -> all zero. Under int32 they are
// k >= 1. (Round-2 evidence: int32 path active; keep the guard regardless.)
__device__ __forceinline__ int load_topk(const void* p, int b) {
    const int* p32 = (const int*)p;
    bool is64 = ((p32[1] | p32[3] | p32[5] | p32[7]) == 0);
    if (is64) {
        long long k64 = ((const long long*)p)[b];
        return (int)k64;
    }
    return p32[b];
}

__global__ __launch_bounds__(NTHREADS) void sampler_kernel(
    const float* __restrict__ logits, const float* __restrict__ temps,
    const void* __restrict__ topks, const float* __restrict__ topps,
    int* __restrict__ out)
{
    __shared__ u32 hist[NBINS];          // 16 KB; reused as expv (float) later
    __shared__ u64 cand[CAP];            // 32 KB
    __shared__ u32 chunkTot[NTHREADS];   // 4 KB
    __shared__ u32 grpTot[64];
    __shared__ u32 grpSufAfter[64];
    __shared__ int sB;
    __shared__ int sCnt;
    __shared__ u64 sBest;
    __shared__ int sJ0, sStart;
    __shared__ float sZ2;
    float* expv = (float*)hist;

    const int b   = blockIdx.x;
    const int tid = threadIdx.x;
    const float temp = temps[b];
    const int k  = min(max(load_topk(topks, b), 1), V);
    const float lim = 1.0f - topps[b];   // f32, same rounding as reference

    for (int i = tid; i < NBINS; i += NTHREADS) hist[i] = 0;
    if (tid == 0) { sCnt = 0; sBest = 0; sB = 0; }
    __syncthreads();

    const float* row = logits + (size_t)b * V;

    // ---- phase 1: histogram of monotone-mapped keys of x = l/temp ----
    for (int v = tid; v < V; v += NTHREADS) {
        float x = row[v] / temp;                 // IEEE f32 div, matches ref
        u32 key = mapkey(x);
        atomicAdd(&hist[key >> 20], 1u);         // top 12 bits -> 4096 bins
    }
    __syncthreads();

    // ---- phase 2: find bin B containing the k-th largest ----
    {
        u32 s = 0; int base = tid << 2;
        #pragma unroll
        for (int i = 0; i < 4; i++) s += hist[base + i];
        chunkTot[tid] = s;
    }
    __syncthreads();
    if (tid < 64) {
        u32 s = 0; int base = tid << 4;
        for (int i = 0; i < 16; i++) s += chunkTot[base + i];
        grpTot[tid] = s;
    }
    __syncthreads();
    if (tid < 64) {
        u32 s = 0;
        for (int g = tid + 1; g < 64; g++) s += grpTot[g];
        grpSufAfter[tid] = s;
    }
    __syncthreads();
    {
        int g = tid >> 4;
        u32 above = grpSufAfter[g];
        int cend = (g << 4) + 16;
        for (int c = tid + 1; c < cend; c++) above += chunkTot[c];
        int base = tid << 2;
        for (int i = 3; i >= 0; i--) {           // scan own bins, high -> low
            u32 h = hist[base + i];
            if (above < (u32)k && above + h >= (u32)k) sB = base + i;
            above += h;
        }
    }
    __syncthreads();
    const int B = sB;

    // ---- phase 3: collect candidates (bin >= B) ----
    for (int v = tid; v < V; v += NTHREADS) {
        float x = row[v] / temp;
        u32 key = mapkey(x);
        if ((int)(key >> 20) >= B) {
            int pos = atomicAdd(&sCnt, 1);
            if (pos < CAP) cand[pos] = ((u64)key << 32) | (u32)v;
        }
    }
    __syncthreads();
    const int m = min(sCnt, CAP);

    // ---- phase 4: bitonic sort candidates ascending by (key, idx) ----
    int P = 1; while (P < m) P <<= 1; if (P < 2) P = 2;
    for (int i = m + tid; i < P; i += NTHREADS) cand[i] = ~0ull;
    __syncthreads();
    for (int len = 2; len <= P; len <<= 1) {
        for (int stride = len >> 1; stride > 0; stride >>= 1) {
            for (int a = tid; a < P; a += NTHREADS) {
                int partner = a ^ stride;
                if (partner > a) {
                    u64 x0 = cand[a], x1 = cand[partner];
                    bool asc = ((a & len) == 0);
                    if ((x0 > x1) == asc) { cand[a] = x1; cand[partner] = x0; }
                }
            }
            __syncthreads();
        }
    }

    // ---- phase 5: top-k kept range [j0, m), exp values ----
    const int kk = (k <= m) ? k : m;
    if (tid == 0) {
        u32 K = (u32)(cand[m - kk] >> 32);
        int j0 = m - kk;
        while (j0 > 0 && (u32)(cand[j0 - 1] >> 32) == K) j0--;  // stable ties
        sJ0 = j0;
    }
    __syncthreads();
    const int j0 = sJ0;
    const int n = m - j0;                       // kept count (<= ~k + ties)
    const float M = unmapkey((u32)(cand[m - 1] >> 32));  // row max
    for (int j = j0 + tid; j < m; j += NTHREADS) {
        float xv = unmapkey((u32)(cand[j] >> 32));
        float d = xv - M;                       // f32 sub, same as ref
        expv[j - j0] = (float)exp((double)d);   // ~correctly-rounded f32 exp
    }
    __syncthreads();

    // ---- phase 6: sequential f32 softmax-cumsum (matches np.cumsum) ----
    if (tid == 0) {
        float Z1 = 0.0f;
        for (int i = 0; i < n; i++) Z1 += expv[i];
        float cum = 0.0f; int lastMasked = -1;
        for (int i = 0; i < n; i++) {
            float p1 = expv[i] / Z1;            // f32 div like ref probs
            cum += p1;                          // sequential f32 cumsum
            if (cum <= lim) lastMasked = i;
        }
        int sstart = lastMasked + 1;
        if (sstart > n - 1) sstart = n - 1;     // always keep top-1
        float Z2 = 0.0f;
        for (int i = sstart; i < n; i++) Z2 += expv[i];
        sStart = sstart; sZ2 = Z2;
    }
    __syncthreads();
    const int sstart = sStart;
    const float Z2 = sZ2;

    // ---- phase 7: survivors -> threefry noise -> argmax(prob/e) ----
    // Modern JAX default: jax_threefry_partitionable=True. Bit stream is
    // per-element counter i (uint64) fed as (hi,lo)=(i>>32, i&0xffffffff);
    // 32-bit output = out0 ^ out1. Here i < 2^32 so hi = 0.
    for (int i = sstart + tid; i < n; i += NTHREADS) {
        float prob = expv[i] / Z2;
        int v = (int)(u32)(cand[j0 + i] & 0xFFFFFFFFu);
        u32 fi = (u32)b * (u32)V + (u32)v;      // flat index, < 2^32
        u32 o0, o1;
        threefry01(0u, fi, o0, o1);
        u32 bits = o0 ^ o1;
        float u = __uint_as_float((bits >> 9) | 0x3F800000u) - 1.0f;
        float e = (float)(-log1p(-(double)u));
        e = fmaxf(e, 1e-10f);
        float r = prob / e;                     // f32 div like ref
        // pack: max r, tie -> smaller original index (ref argmax is first-max)
        u64 pack = ((u64)__float_as_uint(r) << 32) | (u32)(0x7FFFFFFF - v);
        atomicMax(&sBest, pack);
    }
    __syncthreads();
    if (tid == 0) out[b] = 0x7FFFFFFF - (int)(u32)(sBest & 0xFFFFFFFFu);
}

extern "C" void kernel_launch(void* const* d_in, const int* in_sizes, int n_in,
                              void* d_out, int out_size, void* d_ws, size_t ws_size,
                              hipStream_t stream) {
    const float* logits = (const float*)d_in[0];
    const float* temps  = (const float*)d_in[1];
    const void*  topks  = d_in[2];
    const float* topps  = (const float*)d_in[3];
    int* out = (int*)d_out;
    sampler_kernel<<<dim3(128), dim3(NTHREADS), 0, stream>>>(logits, temps, topks, topps, out);
}